// Round 1
// 977.464 us; speedup vs baseline: 1.1729x; 1.1729x over previous
//
#include <hip/hip_runtime.h>
#include <hip/hip_bf16.h>

// Problem constants
#define B_ 256
#define T_ 96
#define F_ 368
#define H_ 368
#define G3_ 1104          // 3*H
#define NC_ 29            // fine classes
#define BT_ (B_*T_)       // 24576
#define HB_ (H_*B_)       // 94208, one time-slice of temporal [u][b]

// GRU geometry
#define NSL 8             // unit slices
#define NU 46             // units per slice (8*46 = 368)
#define NCOL 138          // cols per slice = 3*NU
#define SLSTRIDE 144      // padded col positions per slice (64+64+16)
#define WQCOLS 1152       // 8 * 144
#define ROWS 8            // batch rows per group

#define F4C(v, i) ((i)==0?(v).x:((i)==1?(v).y:((i)==2?(v).z:(v).w)))

typedef __attribute__((ext_vector_type(8))) short bhalf8;   // 8 bf16 = 4 VGPR
typedef __attribute__((ext_vector_type(4))) float f32x4;

// ---- bf16 split helpers (bit-level RNE, no header dependence) -------------
__device__ __forceinline__ unsigned short f2bf(float x) {
    unsigned u = __float_as_uint(x);
    u += 0x7fffu + ((u >> 16) & 1u);
    return (unsigned short)(u >> 16);
}
__device__ __forceinline__ float bf2f(unsigned short b) {
    return __uint_as_float(((unsigned)b) << 16);
}

// async global->LDS, 16B per lane; lds base must be wave-uniform
__device__ __forceinline__ void gll16(const void* g, void* l) {
    __builtin_amdgcn_global_load_lds(
        (const __attribute__((address_space(1))) void*)g,
        (__attribute__((address_space(3))) void*)l, 16, 0, 0);
}

// ---- fence-free cross-XCD exchange primitives (proven in rounds 5/8) ------
__device__ __forceinline__ void bstore_f(float* p, float v) {
    __hip_atomic_store(p, v, __ATOMIC_RELAXED, __HIP_MEMORY_SCOPE_AGENT);
}
__device__ __forceinline__ int bload_i(const int* p) {
    return __hip_atomic_load(p, __ATOMIC_RELAXED, __HIP_MEMORY_SCOPE_AGENT);
}
__device__ __forceinline__ float2 bload_f2(const float* p) {
    unsigned long long v = __hip_atomic_load(
        reinterpret_cast<const unsigned long long*>(p),
        __ATOMIC_RELAXED, __HIP_MEMORY_SCOPE_AGENT);
    float2 f2; __builtin_memcpy(&f2, &v, 8);
    return f2;
}

// ---------------------------------------------------------------------------
// K0: pack Wh (1104x368) into Wq float4 blocks [kb=92][1152 colpos]
// ---------------------------------------------------------------------------
__global__ __launch_bounds__(256) void k_prep_wq(const float* __restrict__ Wh,
                                                 float4* __restrict__ Wq) {
    const int idx = blockIdx.x*256 + threadIdx.x;   // < 92*1152 = 105984
    const int kb = idx / WQCOLS, cp = idx - kb*WQCOLS;
    const int us = cp / SLSTRIDE, r = cp - us*SLSTRIDE;
    float4 v = make_float4(0.f,0.f,0.f,0.f);
    if (r < NCOL) {
        const int g = r / NU, u = r - g*NU;
        const int grow = g*H_ + us*NU + u;          // < 1104
        v = *reinterpret_cast<const float4*>(Wh + (size_t)grow*H_ + 4*kb);
    }
    Wq[idx] = v;
}

// ---------------------------------------------------------------------------
// K0b: pack head weights Wcat[u][32]
// ---------------------------------------------------------------------------
__global__ __launch_bounds__(256) void k_prep_wcat(const float* __restrict__ Wc,
                                                   const float* __restrict__ Wf,
                                                   float* __restrict__ Wcat) {
    const int idx = blockIdx.x*256 + threadIdx.x;   // < 368*32 = 11776
    const int u = idx >> 5, c = idx & 31;
    float v = 0.f;
    if (c < 2) v = Wc[c*H_ + u];
    else if (c < 31) v = Wf[(c-2)*H_ + u];
    Wcat[idx] = v;
}

// ---------------------------------------------------------------------------
// K0c: zero flag words at the coherence point
// ---------------------------------------------------------------------------
__global__ __launch_bounds__(256) void k_zero_bar(int* __restrict__ bar) {
    __hip_atomic_store(bar + blockIdx.x*256 + threadIdx.x, 0,
                       __ATOMIC_RELAXED, __HIP_MEMORY_SCOPE_AGENT);
}

// ---------------------------------------------------------------------------
// K0d: split features (24576x368 f32) into hi/lo bf16 planes (Markidis split).
// x = hi + lo with |lo| <= 2^-9|x|; ah*bh+ah*bl+al*bh recovers ~17 mantissa
// bits -> xproj abs error ~1e-5, below the fp32-reorder noise floor.
// Vectorized float4 in / ushort4 out. 8832*256 threads == 2260992 quads exact.
// ---------------------------------------------------------------------------
__global__ __launch_bounds__(256) void k_split_a(const float* __restrict__ src,
                                                 unsigned short* __restrict__ Ah,
                                                 unsigned short* __restrict__ Al) {
    const int idx = blockIdx.x*256 + threadIdx.x;
    const float4 v = reinterpret_cast<const float4*>(src)[idx];
    ushort4 h, lo;
    h.x = f2bf(v.x); lo.x = f2bf(v.x - bf2f(h.x));
    h.y = f2bf(v.y); lo.y = f2bf(v.y - bf2f(h.y));
    h.z = f2bf(v.z); lo.z = f2bf(v.z - bf2f(h.z));
    h.w = f2bf(v.w); lo.w = f2bf(v.w - bf2f(h.w));
    reinterpret_cast<ushort4*>(Ah)[idx] = h;
    reinterpret_cast<ushort4*>(Al)[idx] = lo;
}

// K0e: split Wi (1104x368) into hi/lo bf16, zero-padded to 1152 N-rows.
// 1656*256 == 423936 == 1152*368 exact.
__global__ __launch_bounds__(256) void k_split_b(const float* __restrict__ Wi,
                                                 unsigned short* __restrict__ Bh,
                                                 unsigned short* __restrict__ Bl) {
    const int idx = blockIdx.x*256 + threadIdx.x;
    const float x = (idx < G3_*F_) ? Wi[idx] : 0.f;
    const unsigned short h = f2bf(x);
    Bh[idx] = h;
    Bl[idx] = f2bf(x - bf2f(h));
}

// ---------------------------------------------------------------------------
// K1: xproj GEMM via split-bf16 MFMA (m97 structure: 128x128 tile, BK=32,
// 4 waves x 4x4 frags of 16x16x32, global_load_lds w=16, 2 barriers/K-step).
// C[m][n] = sum_k feat[m][k]*Wi[n][k]; 3 MFMAs per frag pair (hh, hl, lh).
// K=368 = 11x32 + 16: step 11 stages garbage in k>=368 chunks, which are
// zeroed in LDS before the frag reads (both A and B -> contribute exactly 0).
// XOR chunk swizzle (both-sides: pre-swizzled global src + swizzled ds_read)
// makes the stride-64B frag reads 2-way banked = free.
// ---------------------------------------------------------------------------
__global__ __launch_bounds__(256) void k_xproj_mfma(
        const unsigned short* __restrict__ Ah, const unsigned short* __restrict__ Al,
        const unsigned short* __restrict__ Bh, const unsigned short* __restrict__ Bl,
        const float* __restrict__ bias, float* __restrict__ C)
{
    __shared__ unsigned short sAh[128*32], sAl[128*32], sBh[128*32], sBl[128*32];
    const int tid = threadIdx.x;
    const int w   = tid >> 6, l = tid & 63;
    const int gm0 = blockIdx.y * 128, gn0 = blockIdx.x * 128;

    // staging: thread stages 16B chunks tid and tid+256 per array.
    // chunk c: row = c>>2, lds slot = c&3, global k-chunk = (c&3)^((c>>3)&3)
    // (swizzle s(row) = (row>>1)&3; (tid+256) has identical c&3 and s).
    const int srow = tid >> 2;                       // 0..63
    const int cg   = (tid & 3) ^ ((tid >> 3) & 3);   // source k-chunk (0..3)
    const size_t aoff0 = (size_t)(gm0 + srow)      * F_ + cg * 8;
    const size_t aoff1 = (size_t)(gm0 + srow + 64) * F_ + cg * 8;
    const size_t boff0 = (size_t)(gn0 + srow)      * F_ + cg * 8;
    const size_t boff1 = (size_t)(gn0 + srow + 64) * F_ + cg * 8;
    const int lb0 = w * 1024, lb1 = 4096 + w * 1024; // wave-uniform LDS bases

    // fragment-read LDS byte offsets (fixed across K-steps)
    const int lr = l & 15, lk = l >> 4;              // frag row/col, k-group
    const int cswz = (lk ^ ((lr >> 1) & 3)) * 16;    // swizzled chunk offset
    const int wr = w >> 1, wc = w & 1;               // 2x2 wave grid
    int offA[4], offB[4];
    #pragma unroll
    for (int f = 0; f < 4; ++f) {
        offA[f] = (wr*64 + f*16 + lr) * 64 + cswz;
        offB[f] = (wc*64 + f*16 + lr) * 64 + cswz;
    }

    f32x4 acc[4][4];
    #pragma unroll
    for (int i = 0; i < 4; ++i)
        #pragma unroll
        for (int j = 0; j < 4; ++j) acc[i][j] = f32x4{0.f,0.f,0.f,0.f};

    auto stage = [&](int kt) {
        const size_t ko = (size_t)kt * 32;
        gll16(Ah + aoff0 + ko, (char*)sAh + lb0);
        gll16(Ah + aoff1 + ko, (char*)sAh + lb1);
        gll16(Al + aoff0 + ko, (char*)sAl + lb0);
        gll16(Al + aoff1 + ko, (char*)sAl + lb1);
        gll16(Bh + boff0 + ko, (char*)sBh + lb0);
        gll16(Bh + boff1 + ko, (char*)sBh + lb1);
        gll16(Bl + boff0 + ko, (char*)sBl + lb0);
        gll16(Bl + boff1 + ko, (char*)sBl + lb1);
    };

    stage(0);
    for (int kt = 0; kt < 12; ++kt) {
        __syncthreads();                             // stage(kt) visible
        if (kt == 11) {
            // zero the k>=368 chunks this thread staged (slots tid, tid+256)
            if (cg >= 2) {
                const f32x4 z = f32x4{0.f,0.f,0.f,0.f};
                *reinterpret_cast<f32x4*>((char*)sAh + tid*16)        = z;
                *reinterpret_cast<f32x4*>((char*)sAh + tid*16 + 4096) = z;
                *reinterpret_cast<f32x4*>((char*)sAl + tid*16)        = z;
                *reinterpret_cast<f32x4*>((char*)sAl + tid*16 + 4096) = z;
                *reinterpret_cast<f32x4*>((char*)sBh + tid*16)        = z;
                *reinterpret_cast<f32x4*>((char*)sBh + tid*16 + 4096) = z;
                *reinterpret_cast<f32x4*>((char*)sBl + tid*16)        = z;
                *reinterpret_cast<f32x4*>((char*)sBl + tid*16 + 4096) = z;
            }
            __syncthreads();
        }
        bhalf8 fAh[4], fAl[4], fBh[4], fBl[4];
        #pragma unroll
        for (int f = 0; f < 4; ++f) {
            fAh[f] = *reinterpret_cast<const bhalf8*>((const char*)sAh + offA[f]);
            fAl[f] = *reinterpret_cast<const bhalf8*>((const char*)sAl + offA[f]);
            fBh[f] = *reinterpret_cast<const bhalf8*>((const char*)sBh + offB[f]);
            fBl[f] = *reinterpret_cast<const bhalf8*>((const char*)sBl + offB[f]);
        }
        __syncthreads();                             // reads done, LDS free
        if (kt < 11) stage(kt + 1);                  // loads fly under MFMAs
        #pragma unroll
        for (int i = 0; i < 4; ++i)
            #pragma unroll
            for (int j = 0; j < 4; ++j) {
                acc[i][j] = __builtin_amdgcn_mfma_f32_16x16x32_bf16(fAh[i], fBh[j], acc[i][j], 0, 0, 0);
                acc[i][j] = __builtin_amdgcn_mfma_f32_16x16x32_bf16(fAh[i], fBl[j], acc[i][j], 0, 0, 0);
                acc[i][j] = __builtin_amdgcn_mfma_f32_16x16x32_bf16(fAl[i], fBh[j], acc[i][j], 0, 0, 0);
            }
    }

    // epilogue: C/D layout col = lane&15, row = (lane>>4)*4 + reg
    #pragma unroll
    for (int j = 0; j < 4; ++j) {
        const int gcol = gn0 + wc*64 + j*16 + lr;
        if (gcol < G3_) {
            const float bv = bias[gcol];
            #pragma unroll
            for (int i = 0; i < 4; ++i) {
                const int grow = gm0 + wr*64 + i*16 + lk*4;
                float* cp = C + (size_t)grow * G3_ + gcol;
                #pragma unroll
                for (int q = 0; q < 4; ++q)
                    cp[(size_t)q * G3_] = acc[i][j][q] + bv;
            }
        }
    }
}

// ---------------------------------------------------------------------------
// K2 v8: PERSISTENT GRU (round-8 passing structure, unchanged sync model:
// tid0 spin on single counter -> sync -> cooperative stage -> sync -> FMA ->
// partials -> sync -> gates -> sync -> fetch_add publish). kk=0 W prefetch
// issued BEFORE the spin so its L2 latency hides under the wait.
// ---------------------------------------------------------------------------
__global__ __launch_bounds__(512, 2) void k_gru_all(const float* __restrict__ xproj,
                                                    const float4* __restrict__ Wq,
                                                    const float* __restrict__ bh,
                                                    float* __restrict__ temporal,
                                                    int* __restrict__ bar) {
    __shared__ float part[8][ROWS][SLSTRIDE];   // 36,864 B
    __shared__ float2 hsl2[1472];               // h(t-1)[u][rowpair], 11,776 B
    const int tid = threadIdx.x;
    const int us  = blockIdx.x & 7;             // this WG's slice
    const int bg  = blockIdx.x >> 3;            // 0..31
    const int b0  = bg * ROWS;
    const int w   = tid >> 6;                   // wave 0..7
    const int l   = tid & 63;
    const int l3  = 128 + (l & 15);
    const int off = (23*w + (w & 1)) >> 1;      // kb window start: 0,12,23,35,46,58,69,81
    const int cnt = 12 - (w & 1);               // kb count: 12,11,12,11,...
    int* mybar = bar + bg*64;                   // single counter per bg

    // gate-phase constants (one item per thread, tid < 368)
    const bool gact = tid < ROWS*NU;
    const int u1 = tid % NU, r1 = tid / NU;
    const int ug1 = us*NU + u1;
    float bh1r = 0.f, bh1z = 0.f, bh1n = 0.f;
    if (gact) { bh1r = bh[ug1]; bh1z = bh[H_+ug1]; bh1n = bh[2*H_+ug1]; }

    const float4* wp = Wq + (size_t)off*WQCOLS + us*SLSTRIDE;

    for (int t = 0; t < T_; ++t) {
        float* hout = temporal + (size_t)t*HB_;

        // prefetch gate operands (independent of h; hides under spin)
        float xg10 = 0.f, xg11 = 0.f, xg12 = 0.f;
        if (gact) {
            const float* xr1 = xproj + ((size_t)(b0 + r1)*T_ + t)*G3_;
            xg10 = xr1[ug1]; xg11 = xr1[H_+ug1]; xg12 = xr1[2*H_+ug1];
        }

        float acc[ROWS][3];
        #pragma unroll
        for (int r = 0; r < ROWS; ++r) { acc[r][0]=0.f; acc[r][1]=0.f; acc[r][2]=0.f; }

        if (t > 0) {
            // kk=0 W prefetch BEFORE the spin: static data, L2 latency hides
            // under the flag wait + barriers.
            float4 w0 = wp[l], w1 = wp[64 + l], w2 = wp[l3];
            // proven sync: tid0 spins until all 8 bg-siblings published h(t-1)
            if (tid == 0) {
                while (bload_i(mybar) < 8*t) {}
            }
            __syncthreads();
            const float* hin = temporal + (size_t)(t - 1)*HB_;
            // cooperative stage h(t-1)[368 units][8 rows] as 1472 float2 slots
            #pragma unroll
            for (int ii = 0; ii < 3; ++ii) {
                const int s = tid + ii*512;
                if (s < 1472) {
                    const int u = s >> 2, pr = s & 3;
                    hsl2[s] = bload_f2(hin + (size_t)u*B_ + b0 + 2*pr);
                }
            }
            __syncthreads();
            // inner product over this wave's kb window, W pipelined from L2
            for (int kk = 0; kk < cnt; ++kk) {
                const int kkn = (kk + 1 < cnt) ? kk + 1 : kk;
                const float4* np = wp + (size_t)kkn*WQCOLS;
                const float4 nw0 = np[l], nw1 = np[64 + l], nw2 = np[l3];
                const int ub = 4*(off + kk);
                #pragma unroll
                for (int jk = 0; jk < 4; ++jk) {
                    const int u = ub + jk;
                    const float2 h01 = hsl2[u*4 + 0];
                    const float2 h23 = hsl2[u*4 + 1];
                    const float2 h45 = hsl2[u*4 + 2];
                    const float2 h67 = hsl2[u*4 + 3];
                    const float wa = F4C(w0, jk), wb = F4C(w1, jk), wc2 = F4C(w2, jk);
                    acc[0][0] = fmaf(h01.x, wa, acc[0][0]);
                    acc[0][1] = fmaf(h01.x, wb, acc[0][1]);
                    acc[0][2] = fmaf(h01.x, wc2, acc[0][2]);
                    acc[1][0] = fmaf(h01.y, wa, acc[1][0]);
                    acc[1][1] = fmaf(h01.y, wb, acc[1][1]);
                    acc[1][2] = fmaf(h01.y, wc2, acc[1][2]);
                    acc[2][0] = fmaf(h23.x, wa, acc[2][0]);
                    acc[2][1] = fmaf(h23.x, wb, acc[2][1]);
                    acc[2][2] = fmaf(h23.x, wc2, acc[2][2]);
                    acc[3][0] = fmaf(h23.y, wa, acc[3][0]);
                    acc[3][1] = fmaf(h23.y, wb, acc[3][1]);
                    acc[3][2] = fmaf(h23.y, wc2, acc[3][2]);
                    acc[4][0] = fmaf(h45.x, wa, acc[4][0]);
                    acc[4][1] = fmaf(h45.x, wb, acc[4][1]);
                    acc[4][2] = fmaf(h45.x, wc2, acc[4][2]);
                    acc[5][0] = fmaf(h45.y, wa, acc[5][0]);
                    acc[5][1] = fmaf(h45.y, wb, acc[5][1]);
                    acc[5][2] = fmaf(h45.y, wc2, acc[5][2]);
                    acc[6][0] = fmaf(h67.x, wa, acc[6][0]);
                    acc[6][1] = fmaf(h67.x, wb, acc[6][1]);
                    acc[6][2] = fmaf(h67.x, wc2, acc[6][2]);
                    acc[7][0] = fmaf(h67.y, wa, acc[7][0]);
                    acc[7][1] = fmaf(h67.y, wb, acc[7][1]);
                    acc[7][2] = fmaf(h67.y, wc2, acc[7][2]);
                }
                w0 = nw0; w1 = nw1; w2 = nw2;
            }
        }

        // k-window partials (block3: lane-cousins write identical values)
        #pragma unroll
        for (int r = 0; r < ROWS; ++r) {
            part[w][r][l]      = acc[r][0];
            part[w][r][64 + l] = acc[r][1];
            part[w][r][l3]     = acc[r][2];
        }
        __syncthreads();

        // fused gates: one (unit,row) per thread
        if (gact) {
            float s0 = 0.f, s1 = 0.f, s2 = 0.f;
            #pragma unroll
            for (int q = 0; q < 8; ++q) {
                s0 += part[q][r1][u1];
                s1 += part[q][r1][NU + u1];
                s2 += part[q][r1][2*NU + u1];
            }
            const float rg = 1.f/(1.f + expf(-(xg10 + s0 + bh1r)));
            const float zg = 1.f/(1.f + expf(-(xg11 + s1 + bh1z)));
            const float ng = tanhf(xg12 + rg*(s2 + bh1n));
            float hp = 0.f;
            if (t > 0) {
                const float2 hv = hsl2[ug1*4 + (r1 >> 1)];
                hp = (r1 & 1) ? hv.y : hv.x;
            }
            bstore_f(hout + (size_t)ug1*B_ + b0 + r1, (1.f - zg)*ng + zg*hp);
        }
        // every wave drains vmcnt before s_barrier => all h(t) bypass stores
        // are at the coherence point before the publish below
        __syncthreads();
        if (tid == 0) {
            __hip_atomic_fetch_add(mybar, 1, __ATOMIC_RELAXED,
                                   __HIP_MEMORY_SCOPE_AGENT);
        }
    }
}

// ---------------------------------------------------------------------------
// K3: heads on temporal [t][u][b] (kernel boundary = full visibility)
// ---------------------------------------------------------------------------
__global__ __launch_bounds__(256) void k_heads2(const float* __restrict__ temporal,
                                                const float* __restrict__ Wcat,
                                                const float* __restrict__ bc,
                                                const float* __restrict__ bf,
                                                float* __restrict__ cs,
                                                float* __restrict__ fine_out) {
    const int t = blockIdx.x;       // 0..95
    const int b = threadIdx.x;      // 0..255
    const float* tb = temporal + (size_t)t*HB_ + b;
    float acc[31];
    #pragma unroll
    for (int c = 0; c < 31; ++c) acc[c] = 0.f;
    for (int u = 0; u < H_; ++u) {
        const float x = tb[(size_t)u*B_];
        const float* wrow = Wcat + u*32;
        #pragma unroll
        for (int c = 0; c < 31; ++c) acc[c] = fmaf(x, wrow[c], acc[c]);
    }
    const float l0 = acc[0] + bc[0], l1 = acc[1] + bc[1];
    const float m  = fmaxf(l0, l1);
    const float e0 = expf(l0 - m), e1 = expf(l1 - m);
    const float inv = 1.f/(e0 + e1);
    cs[((size_t)b*T_ + t)*2]     = e0*inv;
    cs[((size_t)b*T_ + t)*2 + 1] = e1*inv;
    #pragma unroll
    for (int c = 2; c < 31; ++c) {
        fine_out[((size_t)b*T_ + t)*NC_ + (c-2)] = 1.f/(1.f + expf(-(acc[c] + bf[c-2])));
    }
}

// ---------------------------------------------------------------------------
// K4: NMS + argmax
// ---------------------------------------------------------------------------
__global__ __launch_bounds__(256) void k_nms(const float* __restrict__ cs,
                                             float* __restrict__ out_dec,
                                             float* __restrict__ out_nms) {
    const int idx = blockIdx.x*256 + threadIdx.x;   // < 24576
    const int t = idx % T_;
    const float bg = cs[idx*2], s1 = cs[idx*2+1];
    float wmin = bg;
    #pragma unroll
    for (int dt = -2; dt <= 2; ++dt) {
        const int tt = t + dt;
        if (dt != 0 && tt >= 0 && tt < T_) wmin = fminf(wmin, cs[(idx + dt)*2]);
    }
    const bool keep = (bg <= wmin);
    out_dec[idx]     = (keep && (s1 > bg)) ? 1.f : 0.f;
    out_nms[idx*2]   = keep ? bg : 0.f;
    out_nms[idx*2+1] = keep ? s1 : 0.f;
}

// ---------------------------------------------------------------------------
extern "C" void kernel_launch(void* const* d_in, const int* in_sizes, int n_in,
                              void* d_out, int out_size, void* d_ws, size_t ws_size,
                              hipStream_t stream) {
    const float* features = (const float*)d_in[0];
    const float* Wi = (const float*)d_in[2];
    const float* Wh = (const float*)d_in[3];
    const float* bi = (const float*)d_in[4];
    const float* bh = (const float*)d_in[5];
    const float* Wc = (const float*)d_in[6];
    const float* bc = (const float*)d_in[7];
    const float* Wf = (const float*)d_in[8];
    const float* bf = (const float*)d_in[9];

    float* out = (float*)d_out;
    float* out_dec  = out;                 // (B,T)     24576
    float* out_nms  = out + BT_;           // (B,T,2)   49152
    float* out_fine = out + BT_ + 2*BT_;   // (B,T,29)  712704

    // workspace (floats): xproj | Wq | temporal | bar (2048 ints)
    float* xproj    = (float*)d_ws;
    float4* Wq      = (float4*)(xproj + (size_t)BT_*G3_);
    float* temporal = xproj + (size_t)BT_*G3_ + (size_t)92*WQCOLS*4;
    int*   bar      = (int*)(temporal + (size_t)T_*HB_);
    float* Wcat     = xproj;               // xproj dead after GRU
    float* cs       = xproj + 12288;

    // phase-1 overlays (dead once consumers below run, stream-ordered):
    //   Bh/Bl (2*1152*368*2B = 1,695,744 B) == Wq region exactly
    //   Ah/Al (2*24576*368*2B = 36,175,872 B) == temporal region exactly
    unsigned short* Bh16 = (unsigned short*)Wq;
    unsigned short* Bl16 = Bh16 + (size_t)WQCOLS*F_;
    unsigned short* Ah16 = (unsigned short*)temporal;
    unsigned short* Al16 = Ah16 + (size_t)BT_*F_;

    k_zero_bar<<<8, 256, 0, stream>>>(bar);
    k_split_a<<<8832, 256, 0, stream>>>(features, Ah16, Al16);
    k_split_b<<<1656, 256, 0, stream>>>(Wi, Bh16, Bl16);
    k_xproj_mfma<<<dim3(9, 192), 256, 0, stream>>>(Ah16, Al16, Bh16, Bl16, bi, xproj);
    k_prep_wq<<<414, 256, 0, stream>>>(Wh, Wq);          // overwrites Bh/Bl (dead)
    k_gru_all<<<256, 512, 0, stream>>>(xproj, Wq, bh, temporal, bar);  // overwrites Ah/Al (dead)
    k_prep_wcat<<<46, 256, 0, stream>>>(Wc, Wf, Wcat);
    k_heads2<<<96, 256, 0, stream>>>(temporal, Wcat, bc, bf, cs, out_fine);
    k_nms<<<96, 256, 0, stream>>>(cs, out_dec, out_nms);
}

// Round 2
// 752.104 us; speedup vs baseline: 1.5243x; 1.2996x over previous
//
#include <hip/hip_runtime.h>
#include <hip/hip_bf16.h>

// Problem constants
#define B_ 256
#define T_ 96
#define F_ 368
#define H_ 368
#define G3_ 1104          // 3*H
#define NC_ 29            // fine classes
#define BT_ (B_*T_)       // 24576
#define HB_ (H_*B_)       // 94208, one time-slice of temporal [u][b]

// GRU geometry
#define NSL 8             // unit slices
#define NU 46             // units per slice (8*46 = 368)
#define NCOL 138          // cols per slice = 3*NU
#define ROWS 8            // batch rows per group
#define WQCOLS 1152       // (legacy name, used for split-B overlay sizing)

// MFMA-GRU geometry: per slice N=138 -> 9 tiles of 16 (cols 138..143 pad),
// K=368 -> 12 k-tiles of 32 (k 368..383 pad). Wq2 frag store:
// [us 8][nt 9][kt 12][plane 2][lane 64][e 8] u16 = 1,769,472 B.
#define WQ2_U16 (8*9*12*2*64*8)

#define F4C(v, i) ((i)==0?(v).x:((i)==1?(v).y:((i)==2?(v).z:(v).w)))

typedef __attribute__((ext_vector_type(8))) short bhalf8;   // 8 bf16 = 4 VGPR
typedef __attribute__((ext_vector_type(4))) float f32x4;

// ---- bf16 split helpers (bit-level RNE, no header dependence) -------------
__device__ __forceinline__ unsigned short f2bf(float x) {
    unsigned u = __float_as_uint(x);
    u += 0x7fffu + ((u >> 16) & 1u);
    return (unsigned short)(u >> 16);
}
__device__ __forceinline__ float bf2f(unsigned short b) {
    return __uint_as_float(((unsigned)b) << 16);
}

// async global->LDS, 16B per lane; lds base must be wave-uniform
__device__ __forceinline__ void gll16(const void* g, void* l) {
    __builtin_amdgcn_global_load_lds(
        (const __attribute__((address_space(1))) void*)g,
        (__attribute__((address_space(3))) void*)l, 16, 0, 0);
}

// ---- fence-free cross-XCD exchange primitives (proven in rounds 5/8) ------
__device__ __forceinline__ int bload_i(const int* p) {
    return __hip_atomic_load(p, __ATOMIC_RELAXED, __HIP_MEMORY_SCOPE_AGENT);
}
__device__ __forceinline__ unsigned int bload_u(const unsigned int* p) {
    return __hip_atomic_load(p, __ATOMIC_RELAXED, __HIP_MEMORY_SCOPE_AGENT);
}
__device__ __forceinline__ void bstore_u(unsigned int* p, unsigned int v) {
    __hip_atomic_store(p, v, __ATOMIC_RELAXED, __HIP_MEMORY_SCOPE_AGENT);
}

// ---------------------------------------------------------------------------
// K0: pack Wh (1104x368) into bf16 hi/lo B-fragments Wq2.
// Element (us,nt,kt,p,lane,e): col = nt*16+(lane&15) slice-local,
// k = kt*32+(lane>>4)*8+e. col<138 && k<368 else 0.
// ---------------------------------------------------------------------------
__global__ __launch_bounds__(256) void k_prep_wq2(const float* __restrict__ Wh,
                                                  unsigned short* __restrict__ Wq2) {
    const int idx = blockIdx.x*256 + threadIdx.x;   // < 110592 (432 blocks exact)
    const int l = idx & 63;
    const int p = (idx >> 6) & 1;
    int q = idx >> 7;
    const int kt = q % 12; q /= 12;
    const int nt = q % 9;
    const int us = q / 9;
    const int col = nt*16 + (l & 15);
    const int k0 = kt*32 + (l >> 4)*8;              // multiple of 8; 368%8==0
    float v[8];
    #pragma unroll
    for (int e = 0; e < 8; ++e) v[e] = 0.f;
    if (col < NCOL && k0 < H_) {
        const int g = col / NU, uu = col - g*NU;
        const int grow = g*H_ + us*NU + uu;         // < 1104
        const float4 f0 = *reinterpret_cast<const float4*>(Wh + (size_t)grow*H_ + k0);
        const float4 f1 = *reinterpret_cast<const float4*>(Wh + (size_t)grow*H_ + k0 + 4);
        v[0]=f0.x; v[1]=f0.y; v[2]=f0.z; v[3]=f0.w;
        v[4]=f1.x; v[5]=f1.y; v[6]=f1.z; v[7]=f1.w;
    }
    unsigned int o[4];
    #pragma unroll
    for (int e = 0; e < 4; ++e) {
        const unsigned short h0 = f2bf(v[2*e]), h1 = f2bf(v[2*e+1]);
        const unsigned short w0 = p ? f2bf(v[2*e]   - bf2f(h0)) : h0;
        const unsigned short w1 = p ? f2bf(v[2*e+1] - bf2f(h1)) : h1;
        o[e] = (unsigned)w0 | ((unsigned)w1 << 16);
    }
    uint4* dst = reinterpret_cast<uint4*>(Wq2 + (size_t)idx*8);
    *dst = make_uint4(o[0], o[1], o[2], o[3]);
}

// ---------------------------------------------------------------------------
// K0b: pack head weights Wcat[u][32]
// ---------------------------------------------------------------------------
__global__ __launch_bounds__(256) void k_prep_wcat(const float* __restrict__ Wc,
                                                   const float* __restrict__ Wf,
                                                   float* __restrict__ Wcat) {
    const int idx = blockIdx.x*256 + threadIdx.x;   // < 368*32 = 11776
    const int u = idx >> 5, c = idx & 31;
    float v = 0.f;
    if (c < 2) v = Wc[c*H_ + u];
    else if (c < 31) v = Wf[(c-2)*H_ + u];
    Wcat[idx] = v;
}

// ---------------------------------------------------------------------------
// K0c: zero flag words at the coherence point
// ---------------------------------------------------------------------------
__global__ __launch_bounds__(256) void k_zero_bar(int* __restrict__ bar) {
    __hip_atomic_store(bar + blockIdx.x*256 + threadIdx.x, 0,
                       __ATOMIC_RELAXED, __HIP_MEMORY_SCOPE_AGENT);
}

// ---------------------------------------------------------------------------
// K0d: split features into hi/lo bf16 planes (Markidis split).
// ---------------------------------------------------------------------------
__global__ __launch_bounds__(256) void k_split_a(const float* __restrict__ src,
                                                 unsigned short* __restrict__ Ah,
                                                 unsigned short* __restrict__ Al) {
    const int idx = blockIdx.x*256 + threadIdx.x;
    const float4 v = reinterpret_cast<const float4*>(src)[idx];
    ushort4 h, lo;
    h.x = f2bf(v.x); lo.x = f2bf(v.x - bf2f(h.x));
    h.y = f2bf(v.y); lo.y = f2bf(v.y - bf2f(h.y));
    h.z = f2bf(v.z); lo.z = f2bf(v.z - bf2f(h.z));
    h.w = f2bf(v.w); lo.w = f2bf(v.w - bf2f(h.w));
    reinterpret_cast<ushort4*>(Ah)[idx] = h;
    reinterpret_cast<ushort4*>(Al)[idx] = lo;
}

// K0e: split Wi (1104x368) into hi/lo bf16, zero-padded to 1152 N-rows.
__global__ __launch_bounds__(256) void k_split_b(const float* __restrict__ Wi,
                                                 unsigned short* __restrict__ Bh,
                                                 unsigned short* __restrict__ Bl) {
    const int idx = blockIdx.x*256 + threadIdx.x;
    const float x = (idx < G3_*F_) ? Wi[idx] : 0.f;
    const unsigned short h = f2bf(x);
    Bh[idx] = h;
    Bl[idx] = f2bf(x - bf2f(h));
}

// ---------------------------------------------------------------------------
// K1: xproj GEMM via split-bf16 MFMA (proven round-1 kernel, unchanged).
// ---------------------------------------------------------------------------
__global__ __launch_bounds__(256) void k_xproj_mfma(
        const unsigned short* __restrict__ Ah, const unsigned short* __restrict__ Al,
        const unsigned short* __restrict__ Bh, const unsigned short* __restrict__ Bl,
        const float* __restrict__ bias, float* __restrict__ C)
{
    __shared__ unsigned short sAh[128*32], sAl[128*32], sBh[128*32], sBl[128*32];
    const int tid = threadIdx.x;
    const int w   = tid >> 6, l = tid & 63;
    const int gm0 = blockIdx.y * 128, gn0 = blockIdx.x * 128;

    const int srow = tid >> 2;                       // 0..63
    const int cg   = (tid & 3) ^ ((tid >> 3) & 3);   // source k-chunk (0..3)
    const size_t aoff0 = (size_t)(gm0 + srow)      * F_ + cg * 8;
    const size_t aoff1 = (size_t)(gm0 + srow + 64) * F_ + cg * 8;
    const size_t boff0 = (size_t)(gn0 + srow)      * F_ + cg * 8;
    const size_t boff1 = (size_t)(gn0 + srow + 64) * F_ + cg * 8;
    const int lb0 = w * 1024, lb1 = 4096 + w * 1024; // wave-uniform LDS bases

    const int lr = l & 15, lk = l >> 4;
    const int cswz = (lk ^ ((lr >> 1) & 3)) * 16;
    const int wr = w >> 1, wc = w & 1;
    int offA[4], offB[4];
    #pragma unroll
    for (int f = 0; f < 4; ++f) {
        offA[f] = (wr*64 + f*16 + lr) * 64 + cswz;
        offB[f] = (wc*64 + f*16 + lr) * 64 + cswz;
    }

    f32x4 acc[4][4];
    #pragma unroll
    for (int i = 0; i < 4; ++i)
        #pragma unroll
        for (int j = 0; j < 4; ++j) acc[i][j] = f32x4{0.f,0.f,0.f,0.f};

    auto stage = [&](int kt) {
        const size_t ko = (size_t)kt * 32;
        gll16(Ah + aoff0 + ko, (char*)sAh + lb0);
        gll16(Ah + aoff1 + ko, (char*)sAh + lb1);
        gll16(Al + aoff0 + ko, (char*)sAl + lb0);
        gll16(Al + aoff1 + ko, (char*)sAl + lb1);
        gll16(Bh + boff0 + ko, (char*)sBh + lb0);
        gll16(Bh + boff1 + ko, (char*)sBh + lb1);
        gll16(Bl + boff0 + ko, (char*)sBl + lb0);
        gll16(Bl + boff1 + ko, (char*)sBl + lb1);
    };

    stage(0);
    for (int kt = 0; kt < 12; ++kt) {
        __syncthreads();
        if (kt == 11) {
            if (cg >= 2) {
                const f32x4 z = f32x4{0.f,0.f,0.f,0.f};
                *reinterpret_cast<f32x4*>((char*)sAh + tid*16)        = z;
                *reinterpret_cast<f32x4*>((char*)sAh + tid*16 + 4096) = z;
                *reinterpret_cast<f32x4*>((char*)sAl + tid*16)        = z;
                *reinterpret_cast<f32x4*>((char*)sAl + tid*16 + 4096) = z;
                *reinterpret_cast<f32x4*>((char*)sBh + tid*16)        = z;
                *reinterpret_cast<f32x4*>((char*)sBh + tid*16 + 4096) = z;
                *reinterpret_cast<f32x4*>((char*)sBl + tid*16)        = z;
                *reinterpret_cast<f32x4*>((char*)sBl + tid*16 + 4096) = z;
            }
            __syncthreads();
        }
        bhalf8 fAh[4], fAl[4], fBh[4], fBl[4];
        #pragma unroll
        for (int f = 0; f < 4; ++f) {
            fAh[f] = *reinterpret_cast<const bhalf8*>((const char*)sAh + offA[f]);
            fAl[f] = *reinterpret_cast<const bhalf8*>((const char*)sAl + offA[f]);
            fBh[f] = *reinterpret_cast<const bhalf8*>((const char*)sBh + offB[f]);
            fBl[f] = *reinterpret_cast<const bhalf8*>((const char*)sBl + offB[f]);
        }
        __syncthreads();
        if (kt < 11) stage(kt + 1);
        #pragma unroll
        for (int i = 0; i < 4; ++i)
            #pragma unroll
            for (int j = 0; j < 4; ++j) {
                acc[i][j] = __builtin_amdgcn_mfma_f32_16x16x32_bf16(fAh[i], fBh[j], acc[i][j], 0, 0, 0);
                acc[i][j] = __builtin_amdgcn_mfma_f32_16x16x32_bf16(fAh[i], fBl[j], acc[i][j], 0, 0, 0);
                acc[i][j] = __builtin_amdgcn_mfma_f32_16x16x32_bf16(fAl[i], fBh[j], acc[i][j], 0, 0, 0);
            }
    }

    #pragma unroll
    for (int j = 0; j < 4; ++j) {
        const int gcol = gn0 + wc*64 + j*16 + lr;
        if (gcol < G3_) {
            const float bv = bias[gcol];
            #pragma unroll
            for (int i = 0; i < 4; ++i) {
                const int grow = gm0 + wr*64 + i*16 + lk*4;
                float* cp = C + (size_t)grow * G3_ + gcol;
                #pragma unroll
                for (int q = 0; q < 4; ++q)
                    cp[(size_t)q * G3_] = acc[i][j][q] + bv;
            }
        }
    }
}

// ---------------------------------------------------------------------------
// K2 v9: PERSISTENT MFMA GRU. Sync model byte-identical to v8 (tid0 spin ->
// sync -> cooperative stage -> sync -> compute -> partials -> sync -> gates
// -> sync -> fetch_add publish). Compute engine replaced:
//  - h published as packed bf16 hi|lo in one u32 (same width/protocol as the
//    old f32 store); heads reconstruct h = hi + lo (err ~2^-17).
//  - Wh lives in VGPRs as pre-split B-fragments (120 VGPR/wave, loaded once):
//    the 1.7 MB/step L2 stream and the per-step W address math are GONE.
//  - per-WG step GEMM out[8rows x 138cols] = 8 waves (2 N-halves x 4 K-
//    quarters) x 45 MFMA 16x16x32 bf16 (3-term Markidis). M-pad rows 8..15
//    read zeroed LDS -> C rows 8..15 = 0, harmless. N-tile 4 computed by
//    both wn halves (identical values, benign double-write).
// ---------------------------------------------------------------------------
__global__ __launch_bounds__(512, 2) void k_gru_all(const float* __restrict__ xproj,
                                                    const unsigned short* __restrict__ Wq2,
                                                    const float* __restrict__ bh,
                                                    unsigned int* __restrict__ h2,
                                                    int* __restrict__ bar) {
    __shared__ unsigned short sAh[48*16*8];     // [k-chunk][row16][e8], 12288 B
    __shared__ unsigned short sAl[48*16*8];     // 12288 B
    __shared__ float part2[4][144][8];          // [wk][col][row], 18432 B
    const int tid = threadIdx.x;
    const int us  = blockIdx.x & 7;             // this WG's slice
    const int bg  = blockIdx.x >> 3;            // 0..31
    const int b0  = bg * ROWS;
    const int w   = tid >> 6;                   // wave 0..7
    const int l   = tid & 63;
    const int wk  = w >> 1;                     // K quarter (3 k-tiles)
    const int wn  = w & 1;                      // N half: tiles wn*4..wn*4+4
    const int nt0 = wn * 4;
    int* mybar = bar + bg*64;

    // zero-init LDS: A pad rows/chunks stay 0 forever; part2 zero for t=0
    for (int s = tid; s < 48*16*8; s += 512) { sAh[s] = 0; sAl[s] = 0; }
    for (int s = tid; s < 4*144*8; s += 512) (&part2[0][0][0])[s] = 0.f;

    // preload static B fragments: 5 tiles x 3 k-tiles x 2 planes = 120 VGPR
    bhalf8 bB[5][3][2];
    #pragma unroll
    for (int ti = 0; ti < 5; ++ti)
        #pragma unroll
        for (int kti = 0; kti < 3; ++kti)
            #pragma unroll
            for (int p = 0; p < 2; ++p)
                bB[ti][kti][p] = *reinterpret_cast<const bhalf8*>(
                    Wq2 + ((((size_t)(us*9 + nt0 + ti)*12 + (wk*3 + kti))*2 + p)*64 + l)*8);

    // gate-phase constants (one item per thread, tid < 368)
    const bool gact = tid < ROWS*NU;
    const int u1 = tid % NU, r1 = tid / NU;
    const int ug1 = us*NU + u1;
    float bh1r = 0.f, bh1z = 0.f, bh1n = 0.f;
    if (gact) { bh1r = bh[ug1]; bh1z = bh[H_+ug1]; bh1n = bh[2*H_+ug1]; }

    // per-lane A-frag LDS byte offset within a k-tile block (1024 B / k-tile)
    const int aoffb = (l >> 4)*256 + (l & 15)*16;

    __syncthreads();

    for (int t = 0; t < T_; ++t) {
        unsigned int* hout = h2 + (size_t)t*HB_;

        // prefetch gate operands (independent of h; hides under spin)
        float xg10 = 0.f, xg11 = 0.f, xg12 = 0.f;
        if (gact) {
            const float* xr1 = xproj + ((size_t)(b0 + r1)*T_ + t)*G3_;
            xg10 = xr1[ug1]; xg11 = xr1[H_+ug1]; xg12 = xr1[2*H_+ug1];
        }

        if (t > 0) {
            // proven sync: tid0 spins until all 8 bg-siblings published h(t-1)
            if (tid == 0) {
                while (bload_i(mybar) < 8*t) {}
            }
            __syncthreads();
            const unsigned int* hin = h2 + (size_t)(t - 1)*HB_;
            // cooperative stage h(t-1): 368 units x 8 rows packed u32 ->
            // LDS A-fragments (chunk = u>>3, row, elem = u&7), hi/lo planes
            #pragma unroll
            for (int ii = 0; ii < 6; ++ii) {
                const int s = tid + ii*512;
                if (s < 2944) {
                    const int u = s >> 3, r = s & 7;
                    const unsigned int v = bload_u(hin + (size_t)u*B_ + b0 + r);
                    const int a = ((u >> 3)*16 + r)*8 + (u & 7);
                    sAh[a] = (unsigned short)(v & 0xffffu);
                    sAl[a] = (unsigned short)(v >> 16);
                }
            }
            __syncthreads();
            // MFMA: 3 k-tiles x 5 n-tiles x 3 split terms = 45 MFMAs/wave
            f32x4 acc[5];
            #pragma unroll
            for (int ti = 0; ti < 5; ++ti) acc[ti] = f32x4{0.f,0.f,0.f,0.f};
            #pragma unroll
            for (int kti = 0; kti < 3; ++kti) {
                const int kt = wk*3 + kti;
                const bhalf8 fh = *reinterpret_cast<const bhalf8*>((const char*)sAh + kt*1024 + aoffb);
                const bhalf8 fl = *reinterpret_cast<const bhalf8*>((const char*)sAl + kt*1024 + aoffb);
                #pragma unroll
                for (int ti = 0; ti < 5; ++ti) {
                    acc[ti] = __builtin_amdgcn_mfma_f32_16x16x32_bf16(fh, bB[ti][kti][0], acc[ti], 0, 0, 0);
                    acc[ti] = __builtin_amdgcn_mfma_f32_16x16x32_bf16(fh, bB[ti][kti][1], acc[ti], 0, 0, 0);
                    acc[ti] = __builtin_amdgcn_mfma_f32_16x16x32_bf16(fl, bB[ti][kti][0], acc[ti], 0, 0, 0);
                }
            }
            // C frags -> per-wk partials. C layout: col=lane&15,
            // row=(lane>>4)*4+reg; real rows 0..7 live in lanes 0..31.
            if (l < 32) {
                #pragma unroll
                for (int ti = 0; ti < 5; ++ti) {
                    const int col = (nt0 + ti)*16 + (l & 15);
                    *reinterpret_cast<f32x4*>(&part2[wk][col][(l >> 4)*4]) = acc[ti];
                }
            }
        }
        __syncthreads();

        // fused gates: one (unit,row) per thread
        if (gact) {
            float s0 = 0.f, s1 = 0.f, s2 = 0.f;
            #pragma unroll
            for (int q2 = 0; q2 < 4; ++q2) {
                s0 += part2[q2][u1][r1];
                s1 += part2[q2][NU + u1][r1];
                s2 += part2[q2][2*NU + u1][r1];
            }
            const float rg = 1.f/(1.f + expf(-(xg10 + s0 + bh1r)));
            const float zg = 1.f/(1.f + expf(-(xg11 + s1 + bh1z)));
            const float ng = tanhf(xg12 + rg*(s2 + bh1n));
            float hp = 0.f;
            if (t > 0) {
                const int a = ((ug1 >> 3)*16 + r1)*8 + (ug1 & 7);
                hp = bf2f(sAh[a]) + bf2f(sAl[a]);
            }
            const float hn = (1.f - zg)*ng + zg*hp;
            const unsigned short hi = f2bf(hn);
            const unsigned short lo = f2bf(hn - bf2f(hi));
            bstore_u(hout + (size_t)ug1*B_ + b0 + r1,
                     (unsigned)hi | ((unsigned)lo << 16));
        }
        // every wave drains vmcnt before s_barrier => all h(t) bypass stores
        // are at the coherence point before the publish below
        __syncthreads();
        if (tid == 0) {
            __hip_atomic_fetch_add(mybar, 1, __ATOMIC_RELAXED,
                                   __HIP_MEMORY_SCOPE_AGENT);
        }
    }
}

// ---------------------------------------------------------------------------
// K3: heads on temporal2 [t][u][b] packed bf16 hi|lo; h = hi + lo.
// ---------------------------------------------------------------------------
__global__ __launch_bounds__(256) void k_heads2(const unsigned int* __restrict__ temporal2,
                                                const float* __restrict__ Wcat,
                                                const float* __restrict__ bc,
                                                const float* __restrict__ bf,
                                                float* __restrict__ cs,
                                                float* __restrict__ fine_out) {
    const int t = blockIdx.x;       // 0..95
    const int b = threadIdx.x;      // 0..255
    const unsigned int* tb = temporal2 + (size_t)t*HB_ + b;
    float acc[31];
    #pragma unroll
    for (int c = 0; c < 31; ++c) acc[c] = 0.f;
    for (int u = 0; u < H_; ++u) {
        const unsigned int v = tb[(size_t)u*B_];
        const float x = bf2f((unsigned short)(v & 0xffffu)) + bf2f((unsigned short)(v >> 16));
        const float* wrow = Wcat + u*32;
        #pragma unroll
        for (int c = 0; c < 31; ++c) acc[c] = fmaf(x, wrow[c], acc[c]);
    }
    const float l0 = acc[0] + bc[0], l1 = acc[1] + bc[1];
    const float m  = fmaxf(l0, l1);
    const float e0 = expf(l0 - m), e1 = expf(l1 - m);
    const float inv = 1.f/(e0 + e1);
    cs[((size_t)b*T_ + t)*2]     = e0*inv;
    cs[((size_t)b*T_ + t)*2 + 1] = e1*inv;
    #pragma unroll
    for (int c = 2; c < 31; ++c) {
        fine_out[((size_t)b*T_ + t)*NC_ + (c-2)] = 1.f/(1.f + expf(-(acc[c] + bf[c-2])));
    }
}

// ---------------------------------------------------------------------------
// K4: NMS + argmax
// ---------------------------------------------------------------------------
__global__ __launch_bounds__(256) void k_nms(const float* __restrict__ cs,
                                             float* __restrict__ out_dec,
                                             float* __restrict__ out_nms) {
    const int idx = blockIdx.x*256 + threadIdx.x;   // < 24576
    const int t = idx % T_;
    const float bg = cs[idx*2], s1 = cs[idx*2+1];
    float wmin = bg;
    #pragma unroll
    for (int dt = -2; dt <= 2; ++dt) {
        const int tt = t + dt;
        if (dt != 0 && tt >= 0 && tt < T_) wmin = fminf(wmin, cs[(idx + dt)*2]);
    }
    const bool keep = (bg <= wmin);
    out_dec[idx]     = (keep && (s1 > bg)) ? 1.f : 0.f;
    out_nms[idx*2]   = keep ? bg : 0.f;
    out_nms[idx*2+1] = keep ? s1 : 0.f;
}

// ---------------------------------------------------------------------------
extern "C" void kernel_launch(void* const* d_in, const int* in_sizes, int n_in,
                              void* d_out, int out_size, void* d_ws, size_t ws_size,
                              hipStream_t stream) {
    const float* features = (const float*)d_in[0];
    const float* Wi = (const float*)d_in[2];
    const float* Wh = (const float*)d_in[3];
    const float* bi = (const float*)d_in[4];
    const float* bh = (const float*)d_in[5];
    const float* Wc = (const float*)d_in[6];
    const float* bc = (const float*)d_in[7];
    const float* Wf = (const float*)d_in[8];
    const float* bf = (const float*)d_in[9];

    float* out = (float*)d_out;
    float* out_dec  = out;                 // (B,T)     24576
    float* out_nms  = out + BT_;           // (B,T,2)   49152
    float* out_fine = out + BT_ + 2*BT_;   // (B,T,29)  712704

    // workspace: xproj f32 | Wq2 u16 frags | temporal2 u32 | bar (2048 ints)
    float* xproj = (float*)d_ws;
    unsigned short* Wq2 = (unsigned short*)(xproj + (size_t)BT_*G3_);
    unsigned int* temporal2 = (unsigned int*)((char*)Wq2 + (size_t)WQ2_U16*2);
    int* bar = (int*)(temporal2 + (size_t)T_*HB_);
    float* Wcat = xproj;                   // xproj dead after GRU
    float* cs   = xproj + 12288;

    // phase-1 overlays (dead once consumers below run, stream-ordered):
    //   Bh/Bl (847,872 u16) fits inside Wq2 region (884,736 u16)
    //   Ah/Al (36,175,872 B) == temporal2 region exactly
    unsigned short* Bh16 = (unsigned short*)Wq2;
    unsigned short* Bl16 = Bh16 + (size_t)WQCOLS*F_;
    unsigned short* Ah16 = (unsigned short*)temporal2;
    unsigned short* Al16 = Ah16 + (size_t)BT_*F_;

    k_zero_bar<<<8, 256, 0, stream>>>(bar);
    k_split_a<<<8832, 256, 0, stream>>>(features, Ah16, Al16);
    k_split_b<<<1656, 256, 0, stream>>>(Wi, Bh16, Bl16);
    k_xproj_mfma<<<dim3(9, 192), 256, 0, stream>>>(Ah16, Al16, Bh16, Bl16, bi, xproj);
    k_prep_wq2<<<432, 256, 0, stream>>>(Wh, Wq2);        // overwrites Bh/Bl (dead)
    k_gru_all<<<256, 512, 0, stream>>>(xproj, Wq2, bh, temporal2, bar); // overwrites Ah/Al (dead)
    k_prep_wcat<<<46, 256, 0, stream>>>(Wc, Wf, Wcat);
    k_heads2<<<96, 256, 0, stream>>>(temporal2, Wcat, bc, bf, cs, out_fine);
    k_nms<<<96, 256, 0, stream>>>(cs, out_dec, out_nms);
}

// Round 3
// 730.740 us; speedup vs baseline: 1.5689x; 1.0292x over previous
//
#include <hip/hip_runtime.h>
#include <hip/hip_bf16.h>

// Problem constants
#define B_ 256
#define T_ 96
#define F_ 368
#define H_ 368
#define G3_ 1104          // 3*H
#define NC_ 29            // fine classes
#define BT_ (B_*T_)       // 24576
#define HB_ (H_*B_)       // 94208, one time-slice of temporal [u][b]

// GRU geometry
#define NSL 8             // unit slices
#define NU 46             // units per slice (8*46 = 368)
#define NCOL 138          // cols per slice = 3*NU
#define ROWS 8            // batch rows per group
#define WQCOLS 1152       // (legacy name, used for split-B overlay sizing)

// MFMA-GRU geometry: per slice N=138 -> 9 tiles of 16 (cols 138..143 pad),
// K=368 -> 12 k-tiles of 32 (k 368..383 pad). Wq2 frag store:
// [us 8][nt 9][kt 12][plane 2][lane 64][e 8] u16 = 1,769,472 B.
#define WQ2_U16 (8*9*12*2*64*8)

#define F4C(v, i) ((i)==0?(v).x:((i)==1?(v).y:((i)==2?(v).z:(v).w)))

typedef __attribute__((ext_vector_type(8))) short bhalf8;   // 8 bf16 = 4 VGPR
typedef __attribute__((ext_vector_type(4))) float f32x4;

// ---- bf16 split helpers (bit-level RNE, no header dependence) -------------
__device__ __forceinline__ unsigned short f2bf(float x) {
    unsigned u = __float_as_uint(x);
    u += 0x7fffu + ((u >> 16) & 1u);
    return (unsigned short)(u >> 16);
}
__device__ __forceinline__ float bf2f(unsigned short b) {
    return __uint_as_float(((unsigned)b) << 16);
}

// async global->LDS, 16B per lane; lds base must be wave-uniform
__device__ __forceinline__ void gll16(const void* g, void* l) {
    __builtin_amdgcn_global_load_lds(
        (const __attribute__((address_space(1))) void*)g,
        (__attribute__((address_space(3))) void*)l, 16, 0, 0);
}

// ---- fence-free cross-XCD exchange primitives (proven in rounds 5/8) ------
__device__ __forceinline__ int bload_i(const int* p) {
    return __hip_atomic_load(p, __ATOMIC_RELAXED, __HIP_MEMORY_SCOPE_AGENT);
}
__device__ __forceinline__ void bstore_i(int* p, int v) {
    __hip_atomic_store(p, v, __ATOMIC_RELAXED, __HIP_MEMORY_SCOPE_AGENT);
}
__device__ __forceinline__ unsigned int bload_u(const unsigned int* p) {
    return __hip_atomic_load(p, __ATOMIC_RELAXED, __HIP_MEMORY_SCOPE_AGENT);
}
__device__ __forceinline__ void bstore_u(unsigned int* p, unsigned int v) {
    __hip_atomic_store(p, v, __ATOMIC_RELAXED, __HIP_MEMORY_SCOPE_AGENT);
}

// ---------------------------------------------------------------------------
// K0: pack Wh (1104x368) into bf16 hi/lo B-fragments Wq2.
// Element (us,nt,kt,p,lane,e): col = nt*16+(lane&15) slice-local,
// k = kt*32+(lane>>4)*8+e. col<138 && k<368 else 0.
// ---------------------------------------------------------------------------
__global__ __launch_bounds__(256) void k_prep_wq2(const float* __restrict__ Wh,
                                                  unsigned short* __restrict__ Wq2) {
    const int idx = blockIdx.x*256 + threadIdx.x;   // < 110592 (432 blocks exact)
    const int l = idx & 63;
    const int p = (idx >> 6) & 1;
    int q = idx >> 7;
    const int kt = q % 12; q /= 12;
    const int nt = q % 9;
    const int us = q / 9;
    const int col = nt*16 + (l & 15);
    const int k0 = kt*32 + (l >> 4)*8;              // multiple of 8; 368%8==0
    float v[8];
    #pragma unroll
    for (int e = 0; e < 8; ++e) v[e] = 0.f;
    if (col < NCOL && k0 < H_) {
        const int g = col / NU, uu = col - g*NU;
        const int grow = g*H_ + us*NU + uu;         // < 1104
        const float4 f0 = *reinterpret_cast<const float4*>(Wh + (size_t)grow*H_ + k0);
        const float4 f1 = *reinterpret_cast<const float4*>(Wh + (size_t)grow*H_ + k0 + 4);
        v[0]=f0.x; v[1]=f0.y; v[2]=f0.z; v[3]=f0.w;
        v[4]=f1.x; v[5]=f1.y; v[6]=f1.z; v[7]=f1.w;
    }
    unsigned int o[4];
    #pragma unroll
    for (int e = 0; e < 4; ++e) {
        const unsigned short h0 = f2bf(v[2*e]), h1 = f2bf(v[2*e+1]);
        const unsigned short w0 = p ? f2bf(v[2*e]   - bf2f(h0)) : h0;
        const unsigned short w1 = p ? f2bf(v[2*e+1] - bf2f(h1)) : h1;
        o[e] = (unsigned)w0 | ((unsigned)w1 << 16);
    }
    uint4* dst = reinterpret_cast<uint4*>(Wq2 + (size_t)idx*8);
    *dst = make_uint4(o[0], o[1], o[2], o[3]);
}

// ---------------------------------------------------------------------------
// K0b: pack head weights Wcat[u][32]
// ---------------------------------------------------------------------------
__global__ __launch_bounds__(256) void k_prep_wcat(const float* __restrict__ Wc,
                                                   const float* __restrict__ Wf,
                                                   float* __restrict__ Wcat) {
    const int idx = blockIdx.x*256 + threadIdx.x;   // < 368*32 = 11776
    const int u = idx >> 5, c = idx & 31;
    float v = 0.f;
    if (c < 2) v = Wc[c*H_ + u];
    else if (c < 31) v = Wf[(c-2)*H_ + u];
    Wcat[idx] = v;
}

// ---------------------------------------------------------------------------
// K0c: zero flag words at the coherence point
// ---------------------------------------------------------------------------
__global__ __launch_bounds__(256) void k_zero_bar(int* __restrict__ bar) {
    __hip_atomic_store(bar + blockIdx.x*256 + threadIdx.x, 0,
                       __ATOMIC_RELAXED, __HIP_MEMORY_SCOPE_AGENT);
}

// ---------------------------------------------------------------------------
// K0d: split features into hi/lo bf16 planes (Markidis split).
// ---------------------------------------------------------------------------
__global__ __launch_bounds__(256) void k_split_a(const float* __restrict__ src,
                                                 unsigned short* __restrict__ Ah,
                                                 unsigned short* __restrict__ Al) {
    const int idx = blockIdx.x*256 + threadIdx.x;
    const float4 v = reinterpret_cast<const float4*>(src)[idx];
    ushort4 h, lo;
    h.x = f2bf(v.x); lo.x = f2bf(v.x - bf2f(h.x));
    h.y = f2bf(v.y); lo.y = f2bf(v.y - bf2f(h.y));
    h.z = f2bf(v.z); lo.z = f2bf(v.z - bf2f(h.z));
    h.w = f2bf(v.w); lo.w = f2bf(v.w - bf2f(h.w));
    reinterpret_cast<ushort4*>(Ah)[idx] = h;
    reinterpret_cast<ushort4*>(Al)[idx] = lo;
}

// K0e: split Wi (1104x368) into hi/lo bf16, zero-padded to 1152 N-rows.
__global__ __launch_bounds__(256) void k_split_b(const float* __restrict__ Wi,
                                                 unsigned short* __restrict__ Bh,
                                                 unsigned short* __restrict__ Bl) {
    const int idx = blockIdx.x*256 + threadIdx.x;
    const float x = (idx < G3_*F_) ? Wi[idx] : 0.f;
    const unsigned short h = f2bf(x);
    Bh[idx] = h;
    Bl[idx] = f2bf(x - bf2f(h));
}

// ---------------------------------------------------------------------------
// K1: xproj GEMM via split-bf16 MFMA (proven round-1 kernel, unchanged).
// ---------------------------------------------------------------------------
__global__ __launch_bounds__(256) void k_xproj_mfma(
        const unsigned short* __restrict__ Ah, const unsigned short* __restrict__ Al,
        const unsigned short* __restrict__ Bh, const unsigned short* __restrict__ Bl,
        const float* __restrict__ bias, float* __restrict__ C)
{
    __shared__ unsigned short sAh[128*32], sAl[128*32], sBh[128*32], sBl[128*32];
    const int tid = threadIdx.x;
    const int w   = tid >> 6, l = tid & 63;
    const int gm0 = blockIdx.y * 128, gn0 = blockIdx.x * 128;

    const int srow = tid >> 2;                       // 0..63
    const int cg   = (tid & 3) ^ ((tid >> 3) & 3);   // source k-chunk (0..3)
    const size_t aoff0 = (size_t)(gm0 + srow)      * F_ + cg * 8;
    const size_t aoff1 = (size_t)(gm0 + srow + 64) * F_ + cg * 8;
    const size_t boff0 = (size_t)(gn0 + srow)      * F_ + cg * 8;
    const size_t boff1 = (size_t)(gn0 + srow + 64) * F_ + cg * 8;
    const int lb0 = w * 1024, lb1 = 4096 + w * 1024; // wave-uniform LDS bases

    const int lr = l & 15, lk = l >> 4;
    const int cswz = (lk ^ ((lr >> 1) & 3)) * 16;
    const int wr = w >> 1, wc = w & 1;
    int offA[4], offB[4];
    #pragma unroll
    for (int f = 0; f < 4; ++f) {
        offA[f] = (wr*64 + f*16 + lr) * 64 + cswz;
        offB[f] = (wc*64 + f*16 + lr) * 64 + cswz;
    }

    f32x4 acc[4][4];
    #pragma unroll
    for (int i = 0; i < 4; ++i)
        #pragma unroll
        for (int j = 0; j < 4; ++j) acc[i][j] = f32x4{0.f,0.f,0.f,0.f};

    auto stage = [&](int kt) {
        const size_t ko = (size_t)kt * 32;
        gll16(Ah + aoff0 + ko, (char*)sAh + lb0);
        gll16(Ah + aoff1 + ko, (char*)sAh + lb1);
        gll16(Al + aoff0 + ko, (char*)sAl + lb0);
        gll16(Al + aoff1 + ko, (char*)sAl + lb1);
        gll16(Bh + boff0 + ko, (char*)sBh + lb0);
        gll16(Bh + boff1 + ko, (char*)sBh + lb1);
        gll16(Bl + boff0 + ko, (char*)sBl + lb0);
        gll16(Bl + boff1 + ko, (char*)sBl + lb1);
    };

    stage(0);
    for (int kt = 0; kt < 12; ++kt) {
        __syncthreads();
        if (kt == 11) {
            if (cg >= 2) {
                const f32x4 z = f32x4{0.f,0.f,0.f,0.f};
                *reinterpret_cast<f32x4*>((char*)sAh + tid*16)        = z;
                *reinterpret_cast<f32x4*>((char*)sAh + tid*16 + 4096) = z;
                *reinterpret_cast<f32x4*>((char*)sAl + tid*16)        = z;
                *reinterpret_cast<f32x4*>((char*)sAl + tid*16 + 4096) = z;
                *reinterpret_cast<f32x4*>((char*)sBh + tid*16)        = z;
                *reinterpret_cast<f32x4*>((char*)sBh + tid*16 + 4096) = z;
                *reinterpret_cast<f32x4*>((char*)sBl + tid*16)        = z;
                *reinterpret_cast<f32x4*>((char*)sBl + tid*16 + 4096) = z;
            }
            __syncthreads();
        }
        bhalf8 fAh[4], fAl[4], fBh[4], fBl[4];
        #pragma unroll
        for (int f = 0; f < 4; ++f) {
            fAh[f] = *reinterpret_cast<const bhalf8*>((const char*)sAh + offA[f]);
            fAl[f] = *reinterpret_cast<const bhalf8*>((const char*)sAl + offA[f]);
            fBh[f] = *reinterpret_cast<const bhalf8*>((const char*)sBh + offB[f]);
            fBl[f] = *reinterpret_cast<const bhalf8*>((const char*)sBl + offB[f]);
        }
        __syncthreads();
        if (kt < 11) stage(kt + 1);
        #pragma unroll
        for (int i = 0; i < 4; ++i)
            #pragma unroll
            for (int j = 0; j < 4; ++j) {
                acc[i][j] = __builtin_amdgcn_mfma_f32_16x16x32_bf16(fAh[i], fBh[j], acc[i][j], 0, 0, 0);
                acc[i][j] = __builtin_amdgcn_mfma_f32_16x16x32_bf16(fAh[i], fBl[j], acc[i][j], 0, 0, 0);
                acc[i][j] = __builtin_amdgcn_mfma_f32_16x16x32_bf16(fAl[i], fBh[j], acc[i][j], 0, 0, 0);
            }
    }

    #pragma unroll
    for (int j = 0; j < 4; ++j) {
        const int gcol = gn0 + wc*64 + j*16 + lr;
        if (gcol < G3_) {
            const float bv = bias[gcol];
            #pragma unroll
            for (int i = 0; i < 4; ++i) {
                const int grow = gm0 + wr*64 + i*16 + lk*4;
                float* cp = C + (size_t)grow * G3_ + gcol;
                #pragma unroll
                for (int q = 0; q < 4; ++q)
                    cp[(size_t)q * G3_] = acc[i][j][q] + bv;
            }
        }
    }
}

// ---------------------------------------------------------------------------
// K2 v10: PERSISTENT MFMA GRU, shortened sync chain.
// Changes vs v9 (arithmetic bit-identical):
//  - per-slice FLAGS (plain bypass stores) replace the single fetch_add
//    counter: tid0 stores flags[us]=t+1 AFTER the same drain barrier. Same
//    release argument (vmcnt drained at barrier => h stores at coherence
//    point before the later flag store). No RMW serialization.
//  - per-wave poll+stage: wave w polls flags[w] and stages slice w itself.
//    Deletes the tid0-spin + wake barrier; early slices stage under the
//    wait for late ones (skew absorbed, not summed).
//  - part2 padded [4][144][9]: col stride 36 B, 9 coprime 32 -> partials
//    writes and gate reads bank-conflict-free (was 4-way).
// ---------------------------------------------------------------------------
__global__ __launch_bounds__(512, 2) void k_gru_all(const float* __restrict__ xproj,
                                                    const unsigned short* __restrict__ Wq2,
                                                    const float* __restrict__ bh,
                                                    unsigned int* __restrict__ h2,
                                                    int* __restrict__ bar) {
    __shared__ unsigned short sAh[48*16*8];     // [k-chunk][row16][e8], 12288 B
    __shared__ unsigned short sAl[48*16*8];     // 12288 B
    __shared__ float part2[4][144][9];          // [wk][col][row+pad], 20736 B
    const int tid = threadIdx.x;
    const int us  = blockIdx.x & 7;             // this WG's slice
    const int bg  = blockIdx.x >> 3;            // 0..31
    const int b0  = bg * ROWS;
    const int w   = tid >> 6;                   // wave 0..7
    const int l   = tid & 63;
    const int wk  = w >> 1;                     // K quarter (3 k-tiles)
    const int wn  = w & 1;                      // N half: tiles wn*4..wn*4+4
    const int nt0 = wn * 4;
    int* flags = bar + bg*64;                   // words 0..7 = slice flags
    int* myflag = flags + us;

    // zero-init LDS: A pad rows/chunks stay 0 forever; part2 zero for t=0
    for (int s = tid; s < 48*16*8; s += 512) { sAh[s] = 0; sAl[s] = 0; }
    for (int s = tid; s < 4*144*9; s += 512) (&part2[0][0][0])[s] = 0.f;

    // preload static B fragments: 5 tiles x 3 k-tiles x 2 planes = 120 VGPR
    bhalf8 bB[5][3][2];
    #pragma unroll
    for (int ti = 0; ti < 5; ++ti)
        #pragma unroll
        for (int kti = 0; kti < 3; ++kti)
            #pragma unroll
            for (int p = 0; p < 2; ++p)
                bB[ti][kti][p] = *reinterpret_cast<const bhalf8*>(
                    Wq2 + ((((size_t)(us*9 + nt0 + ti)*12 + (wk*3 + kti))*2 + p)*64 + l)*8);

    // gate-phase constants (one item per thread, tid < 368)
    const bool gact = tid < ROWS*NU;
    const int u1 = tid % NU, r1 = tid / NU;
    const int ug1 = us*NU + u1;
    float bh1r = 0.f, bh1z = 0.f, bh1n = 0.f;
    if (gact) { bh1r = bh[ug1]; bh1z = bh[H_+ug1]; bh1n = bh[2*H_+ug1]; }

    // per-lane A-frag LDS byte offset within a k-tile block (1024 B / k-tile)
    const int aoffb = (l >> 4)*256 + (l & 15)*16;

    __syncthreads();

    for (int t = 0; t < T_; ++t) {
        unsigned int* hout = h2 + (size_t)t*HB_;

        // prefetch gate operands (independent of h; hides under poll)
        float xg10 = 0.f, xg11 = 0.f, xg12 = 0.f;
        if (gact) {
            const float* xr1 = xproj + ((size_t)(b0 + r1)*T_ + t)*G3_;
            xg10 = xr1[ug1]; xg11 = xr1[H_+ug1]; xg12 = xr1[2*H_+ug1];
        }

        if (t > 0) {
            // wave w: wait for slice-w producer, then stage slice w.
            // (flags monotone; relaxed agent loads; exit => producer's h(t-1)
            // stores are at the coherence point per the release argument)
            while (bload_i(flags + w) < t) {}
            const unsigned int* hin = h2 + (size_t)(t - 1)*HB_;
            #pragma unroll
            for (int ii = 0; ii < 6; ++ii) {
                const int sl = l + ii*64;
                if (sl < NSL*NU) {          // 368 u32 per slice
                    const int u = NU*w + (sl >> 3), r = sl & 7;
                    const unsigned int v = bload_u(hin + (size_t)u*B_ + b0 + r);
                    const int a = ((u >> 3)*16 + r)*8 + (u & 7);
                    sAh[a] = (unsigned short)(v & 0xffffu);
                    sAl[a] = (unsigned short)(v >> 16);
                }
            }
            __syncthreads();
            // MFMA: 3 k-tiles x 5 n-tiles x 3 split terms = 45 MFMAs/wave
            f32x4 acc[5];
            #pragma unroll
            for (int ti = 0; ti < 5; ++ti) acc[ti] = f32x4{0.f,0.f,0.f,0.f};
            #pragma unroll
            for (int kti = 0; kti < 3; ++kti) {
                const int kt = wk*3 + kti;
                const bhalf8 fh = *reinterpret_cast<const bhalf8*>((const char*)sAh + kt*1024 + aoffb);
                const bhalf8 fl = *reinterpret_cast<const bhalf8*>((const char*)sAl + kt*1024 + aoffb);
                #pragma unroll
                for (int ti = 0; ti < 5; ++ti) {
                    acc[ti] = __builtin_amdgcn_mfma_f32_16x16x32_bf16(fh, bB[ti][kti][0], acc[ti], 0, 0, 0);
                    acc[ti] = __builtin_amdgcn_mfma_f32_16x16x32_bf16(fh, bB[ti][kti][1], acc[ti], 0, 0, 0);
                    acc[ti] = __builtin_amdgcn_mfma_f32_16x16x32_bf16(fl, bB[ti][kti][0], acc[ti], 0, 0, 0);
                }
            }
            // C frags -> per-wk partials (padded, conflict-free).
            // C layout: col=lane&15, row=(lane>>4)*4+reg; rows 0..7 in lanes 0..31.
            if (l < 32) {
                #pragma unroll
                for (int ti = 0; ti < 5; ++ti) {
                    const int col = (nt0 + ti)*16 + (l & 15);
                    float* pp = &part2[wk][col][(l >> 4)*4];
                    pp[0] = acc[ti][0]; pp[1] = acc[ti][1];
                    pp[2] = acc[ti][2]; pp[3] = acc[ti][3];
                }
            }
        }
        __syncthreads();

        // fused gates: one (unit,row) per thread
        if (gact) {
            float s0 = 0.f, s1 = 0.f, s2 = 0.f;
            #pragma unroll
            for (int q2 = 0; q2 < 4; ++q2) {
                s0 += part2[q2][u1][r1];
                s1 += part2[q2][NU + u1][r1];
                s2 += part2[q2][2*NU + u1][r1];
            }
            const float rg = 1.f/(1.f + expf(-(xg10 + s0 + bh1r)));
            const float zg = 1.f/(1.f + expf(-(xg11 + s1 + bh1z)));
            const float ng = tanhf(xg12 + rg*(s2 + bh1n));
            float hp = 0.f;
            if (t > 0) {
                const int a = ((ug1 >> 3)*16 + r1)*8 + (ug1 & 7);
                hp = bf2f(sAh[a]) + bf2f(sAl[a]);
            }
            const float hn = (1.f - zg)*ng + zg*hp;
            const unsigned short hi = f2bf(hn);
            const unsigned short lo = f2bf(hn - bf2f(hi));
            bstore_u(hout + (size_t)ug1*B_ + b0 + r1,
                     (unsigned)hi | ((unsigned)lo << 16));
        }
        // every wave drains vmcnt before s_barrier => all h(t) bypass stores
        // are at the coherence point before the flag store below.
        // This barrier also guards sAh WAR (gates' hp reads precede it).
        __syncthreads();
        if (tid == 0) bstore_i(myflag, t + 1);
    }
}

// ---------------------------------------------------------------------------
// K3: heads on temporal2 [t][u][b] packed bf16 hi|lo; h = hi + lo.
// ---------------------------------------------------------------------------
__global__ __launch_bounds__(256) void k_heads2(const unsigned int* __restrict__ temporal2,
                                                const float* __restrict__ Wcat,
                                                const float* __restrict__ bc,
                                                const float* __restrict__ bf,
                                                float* __restrict__ cs,
                                                float* __restrict__ fine_out) {
    const int t = blockIdx.x;       // 0..95
    const int b = threadIdx.x;      // 0..255
    const unsigned int* tb = temporal2 + (size_t)t*HB_ + b;
    float acc[31];
    #pragma unroll
    for (int c = 0; c < 31; ++c) acc[c] = 0.f;
    for (int u = 0; u < H_; ++u) {
        const unsigned int v = tb[(size_t)u*B_];
        const float x = bf2f((unsigned short)(v & 0xffffu)) + bf2f((unsigned short)(v >> 16));
        const float* wrow = Wcat + u*32;
        #pragma unroll
        for (int c = 0; c < 31; ++c) acc[c] = fmaf(x, wrow[c], acc[c]);
    }
    const float l0 = acc[0] + bc[0], l1 = acc[1] + bc[1];
    const float m  = fmaxf(l0, l1);
    const float e0 = expf(l0 - m), e1 = expf(l1 - m);
    const float inv = 1.f/(e0 + e1);
    cs[((size_t)b*T_ + t)*2]     = e0*inv;
    cs[((size_t)b*T_ + t)*2 + 1] = e1*inv;
    #pragma unroll
    for (int c = 2; c < 31; ++c) {
        fine_out[((size_t)b*T_ + t)*NC_ + (c-2)] = 1.f/(1.f + expf(-(acc[c] + bf[c-2])));
    }
}

// ---------------------------------------------------------------------------
// K4: NMS + argmax
// ---------------------------------------------------------------------------
__global__ __launch_bounds__(256) void k_nms(const float* __restrict__ cs,
                                             float* __restrict__ out_dec,
                                             float* __restrict__ out_nms) {
    const int idx = blockIdx.x*256 + threadIdx.x;   // < 24576
    const int t = idx % T_;
    const float bg = cs[idx*2], s1 = cs[idx*2+1];
    float wmin = bg;
    #pragma unroll
    for (int dt = -2; dt <= 2; ++dt) {
        const int tt = t + dt;
        if (dt != 0 && tt >= 0 && tt < T_) wmin = fminf(wmin, cs[(idx + dt)*2]);
    }
    const bool keep = (bg <= wmin);
    out_dec[idx]     = (keep && (s1 > bg)) ? 1.f : 0.f;
    out_nms[idx*2]   = keep ? bg : 0.f;
    out_nms[idx*2+1] = keep ? s1 : 0.f;
}

// ---------------------------------------------------------------------------
extern "C" void kernel_launch(void* const* d_in, const int* in_sizes, int n_in,
                              void* d_out, int out_size, void* d_ws, size_t ws_size,
                              hipStream_t stream) {
    const float* features = (const float*)d_in[0];
    const float* Wi = (const float*)d_in[2];
    const float* Wh = (const float*)d_in[3];
    const float* bi = (const float*)d_in[4];
    const float* bh = (const float*)d_in[5];
    const float* Wc = (const float*)d_in[6];
    const float* bc = (const float*)d_in[7];
    const float* Wf = (const float*)d_in[8];
    const float* bf = (const float*)d_in[9];

    float* out = (float*)d_out;
    float* out_dec  = out;                 // (B,T)     24576
    float* out_nms  = out + BT_;           // (B,T,2)   49152
    float* out_fine = out + BT_ + 2*BT_;   // (B,T,29)  712704

    // workspace: xproj f32 | Wq2 u16 frags | temporal2 u32 | bar (2048 ints)
    float* xproj = (float*)d_ws;
    unsigned short* Wq2 = (unsigned short*)(xproj + (size_t)BT_*G3_);
    unsigned int* temporal2 = (unsigned int*)((char*)Wq2 + (size_t)WQ2_U16*2);
    int* bar = (int*)(temporal2 + (size_t)T_*HB_);
    float* Wcat = xproj;                   // xproj dead after GRU
    float* cs   = xproj + 12288;

    // phase-1 overlays (dead once consumers below run, stream-ordered):
    //   Bh/Bl (847,872 u16) fits inside Wq2 region (884,736 u16)
    //   Ah/Al (36,175,872 B) == temporal2 region exactly
    unsigned short* Bh16 = (unsigned short*)Wq2;
    unsigned short* Bl16 = Bh16 + (size_t)WQCOLS*F_;
    unsigned short* Ah16 = (unsigned short*)temporal2;
    unsigned short* Al16 = Ah16 + (size_t)BT_*F_;

    k_zero_bar<<<8, 256, 0, stream>>>(bar);
    k_split_a<<<8832, 256, 0, stream>>>(features, Ah16, Al16);
    k_split_b<<<1656, 256, 0, stream>>>(Wi, Bh16, Bl16);
    k_xproj_mfma<<<dim3(9, 192), 256, 0, stream>>>(Ah16, Al16, Bh16, Bl16, bi, xproj);
    k_prep_wq2<<<432, 256, 0, stream>>>(Wh, Wq2);        // overwrites Bh/Bl (dead)
    k_gru_all<<<256, 512, 0, stream>>>(xproj, Wq2, bh, temporal2, bar); // overwrites Ah/Al (dead)
    k_prep_wcat<<<46, 256, 0, stream>>>(Wc, Wf, Wcat);
    k_heads2<<<96, 256, 0, stream>>>(temporal2, Wcat, bc, bf, cs, out_fine);
    k_nms<<<96, 256, 0, stream>>>(cs, out_dec, out_nms);
}